// Round 1
// baseline (882.414 us; speedup 1.0000x reference)
//
#include <hip/hip_runtime.h>
#include <hip/hip_bf16.h>
#include <stdint.h>

// Problem constants (from reference)
#define IN_FEATURES 4096
#define OUT_FEATURES 11008
#define M_ROWS 8192              // 4 * 2048
#define NUM_IN_GROUPS 512        // IN_FEATURES / IN_GROUP(8)
#define CB_SIZE 256

typedef _Float16 f16x8 __attribute__((ext_vector_type(8)));
typedef float f32x4 __attribute__((ext_vector_type(4)));

// ---------------------------------------------------------------------------
// Kernel 1: dequantize W (UNSCALED: scales applied in GEMM epilogue in fp32).
// W[o][g*8+j] = cb[0][codes[o][g][0]][j] + cb[1][codes[o][g][1]][j]
// One thread per (o,g) group: 11008*512 = 5,636,096 threads.
// ---------------------------------------------------------------------------
__global__ __launch_bounds__(256) void dequant_w_kernel(
    const int* __restrict__ codes, const float* __restrict__ cbs,
    _Float16* __restrict__ W)
{
  const int idx = blockIdx.x * 256 + threadIdx.x;   // o*512 + g (exact grid)
  const int2 c = ((const int2*)codes)[idx];
  const float4* e0 = (const float4*)(cbs + (size_t)c.x * 8);
  const float4* e1 = (const float4*)(cbs + (size_t)CB_SIZE * 8 + (size_t)c.y * 8);
  const float4 a0 = e0[0], a1 = e0[1];
  const float4 b0 = e1[0], b1 = e1[1];
  f16x8 w;
  w[0] = (_Float16)(a0.x + b0.x);
  w[1] = (_Float16)(a0.y + b0.y);
  w[2] = (_Float16)(a0.z + b0.z);
  w[3] = (_Float16)(a0.w + b0.w);
  w[4] = (_Float16)(a1.x + b1.x);
  w[5] = (_Float16)(a1.y + b1.y);
  w[6] = (_Float16)(a1.z + b1.z);
  w[7] = (_Float16)(a1.w + b1.w);
  *(f16x8*)(W + (size_t)idx * 8) = w;
}

// ---------------------------------------------------------------------------
// Kernel 2: x fp32 -> f16, 8 elems/thread, vectorized.
// ---------------------------------------------------------------------------
__global__ __launch_bounds__(256) void convert_x_kernel(
    const float* __restrict__ x, _Float16* __restrict__ X)
{
  const size_t i = ((size_t)blockIdx.x * 256 + threadIdx.x) * 8;
  const float4 a = *(const float4*)(x + i);
  const float4 b = *(const float4*)(x + i + 4);
  f16x8 v;
  v[0] = (_Float16)a.x; v[1] = (_Float16)a.y;
  v[2] = (_Float16)a.z; v[3] = (_Float16)a.w;
  v[4] = (_Float16)b.x; v[5] = (_Float16)b.y;
  v[6] = (_Float16)b.z; v[7] = (_Float16)b.w;
  *(f16x8*)(X + i) = v;
}

// ---------------------------------------------------------------------------
// Kernel 3: f16 MFMA GEMM, m97 structure.
// out[m][o] = (sum_k X[m][k]*W[o][k]) * scales[o] + bias[o]
// Tile 128x128, BK=64, 256 threads = 4 waves in 2x2, each wave 64x64 output.
// global_load_lds width-16 staging (linear LDS dest), 2 barriers per K-step.
// MFMA: v_mfma_f32_16x16x32_f16; A-frag row=lane&15, k=(lane>>4)*8+j;
// C/D: col=lane&15, row=(lane>>4)*4+reg (m89-verified, dtype-independent).
// ---------------------------------------------------------------------------
#define BM 128
#define BN 128
#define BK 64
#define NT_M (M_ROWS / BM)       // 64 M-tiles; n-panel outer for L2/L3 reuse

__global__ __launch_bounds__(256, 2) void gemm_f16_kernel(
    const _Float16* __restrict__ X, const _Float16* __restrict__ W,
    const float* __restrict__ scales, const float* __restrict__ bias,
    float* __restrict__ out)
{
  __shared__ _Float16 lds_a[BM * BK];   // 16 KB, linear [row][k]
  __shared__ _Float16 lds_b[BN * BK];   // 16 KB

  const int nt = blockIdx.x / NT_M;
  const int mt = blockIdx.x % NT_M;
  const int m0 = mt * BM, n0 = nt * BN;
  const int lane = threadIdx.x & 63;
  const int wave = threadIdx.x >> 6;
  const int wm = wave >> 1, wn = wave & 1;
  const int r16 = lane & 15;
  const int koff = (lane >> 4) * 8;

  f32x4 acc[4][4] = {};

  for (int kt = 0; kt < IN_FEATURES / BK; ++kt) {
    __syncthreads();                       // previous compute done before overwrite
    const size_t kb = (size_t)kt * BK;
    // Stage A: 1024 16B-chunks, 4 issues/wave, LDS dest wave-uniform + lane*16
    #pragma unroll
    for (int it = 0; it < 4; ++it) {
      const int cbase = (wave * 4 + it) * 64;
      const int c = cbase + lane;
      const int row = c >> 3;
      const int col = (c & 7) * 8;
      __builtin_amdgcn_global_load_lds(
          (const __attribute__((address_space(1))) void*)(X + (size_t)(m0 + row) * IN_FEATURES + kb + col),
          (__attribute__((address_space(3))) void*)(lds_a + (size_t)cbase * 8),
          16, 0, 0);
    }
    #pragma unroll
    for (int it = 0; it < 4; ++it) {
      const int cbase = (wave * 4 + it) * 64;
      const int c = cbase + lane;
      const int row = c >> 3;
      const int col = (c & 7) * 8;
      __builtin_amdgcn_global_load_lds(
          (const __attribute__((address_space(1))) void*)(W + (size_t)(n0 + row) * IN_FEATURES + kb + col),
          (__attribute__((address_space(3))) void*)(lds_b + (size_t)cbase * 8),
          16, 0, 0);
    }
    __syncthreads();                       // compiler drains vmcnt(0) before barrier

    #pragma unroll
    for (int kk = 0; kk < BK; kk += 32) {
      f16x8 af[4], bf[4];
      #pragma unroll
      for (int m = 0; m < 4; ++m)
        af[m] = *(const f16x8*)(lds_a + (wm * 64 + m * 16 + r16) * BK + kk + koff);
      #pragma unroll
      for (int n = 0; n < 4; ++n)
        bf[n] = *(const f16x8*)(lds_b + (wn * 64 + n * 16 + r16) * BK + kk + koff);
      #pragma unroll
      for (int m = 0; m < 4; ++m) {
        #pragma unroll
        for (int n = 0; n < 4; ++n)
          acc[m][n] = __builtin_amdgcn_mfma_f32_16x16x32_f16(af[m], bf[n], acc[m][n], 0, 0, 0);
      }
    }
  }

  // Epilogue: acc * scales[col] + bias[col], fp32
  const int crow = (lane >> 4) * 4;
  #pragma unroll
  for (int n = 0; n < 4; ++n) {
    const int col = n0 + wn * 64 + n * 16 + r16;
    const float s = scales[col];
    const float bb = bias[col];
    #pragma unroll
    for (int m = 0; m < 4; ++m) {
      const int rowb = m0 + wm * 64 + m * 16 + crow;
      #pragma unroll
      for (int r = 0; r < 4; ++r)
        out[(size_t)(rowb + r) * OUT_FEATURES + col] = acc[m][n][r] * s + bb;
    }
  }
}

// ---------------------------------------------------------------------------
// Fallback (only if ws too small): correct but slow fp32 path.
// One block per row m; x row staged in LDS; threads stride over out features.
// ---------------------------------------------------------------------------
__global__ __launch_bounds__(256) void naive_kernel(
    const float* __restrict__ x, const int* __restrict__ codes,
    const float* __restrict__ cbs, const float* __restrict__ scales,
    const float* __restrict__ bias, float* __restrict__ out)
{
  __shared__ float xrow[IN_FEATURES];
  const int m = blockIdx.x;
  for (int i = threadIdx.x; i < IN_FEATURES; i += 256)
    xrow[i] = x[(size_t)m * IN_FEATURES + i];
  __syncthreads();
  for (int o = threadIdx.x; o < OUT_FEATURES; o += 256) {
    float acc = 0.f;
    const int2* crow = (const int2*)codes + (size_t)o * NUM_IN_GROUPS;
    for (int g = 0; g < NUM_IN_GROUPS; ++g) {
      const int2 c = crow[g];
      const float* e0 = cbs + (size_t)c.x * 8;
      const float* e1 = cbs + (size_t)CB_SIZE * 8 + (size_t)c.y * 8;
      const float* xr = xrow + g * 8;
      #pragma unroll
      for (int j = 0; j < 8; ++j) acc += (e0[j] + e1[j]) * xr[j];
    }
    out[(size_t)m * OUT_FEATURES + o] = acc * scales[o] + bias[o];
  }
}

// ---------------------------------------------------------------------------
extern "C" void kernel_launch(void* const* d_in, const int* in_sizes, int n_in,
                              void* d_out, int out_size, void* d_ws, size_t ws_size,
                              hipStream_t stream) {
  const float* x      = (const float*)d_in[0];
  const int*   codes  = (const int*)d_in[1];
  const float* cbs    = (const float*)d_in[2];
  const float* scales = (const float*)d_in[3];
  const float* bias   = (const float*)d_in[4];
  float* out = (float*)d_out;

  const size_t W_BYTES = (size_t)OUT_FEATURES * IN_FEATURES * sizeof(_Float16); // 90.2 MB
  const size_t X_BYTES = (size_t)M_ROWS * IN_FEATURES * sizeof(_Float16);       // 67.1 MB

  if (ws_size < W_BYTES + X_BYTES) {
    // Emergency correct path (no workspace dependence)
    naive_kernel<<<M_ROWS, 256, 0, stream>>>(x, codes, cbs, scales, bias, out);
    return;
  }

  _Float16* W = (_Float16*)d_ws;
  _Float16* X = (_Float16*)((char*)d_ws + W_BYTES);

  dequant_w_kernel<<<(OUT_FEATURES * NUM_IN_GROUPS) / 256, 256, 0, stream>>>(codes, cbs, W);
  convert_x_kernel<<<(M_ROWS * IN_FEATURES / 8) / 256, 256, 0, stream>>>(x, X);
  gemm_f16_kernel<<<(M_ROWS / BM) * (OUT_FEATURES / BN), 256, 0, stream>>>(X, W, scales, bias, out);
}